// Round 9
// baseline (159.643 us; speedup 1.0000x reference)
//
#include <hip/hip_runtime.h>

#define N_IMG   1024
#define N_VIEWS 90
#define CENTER  512
#define TILE    64
#define NTILES  16                  // y-tiles per block
#define NTHREADS 512
#define NWAVES   8
#define YPT      (TILE / NWAVES)    // 8 samples per thread per tile
#define BUF_WORDS 9216              // 92 rows * stride<=97 + drift pad (36.9 KB)

extern __shared__ float smem[];     // 2 * BUF_WORDS floats (double buffer)

// x_in =  ca*X + sa*Y + cx,  cx = CENTER*(1 - ca - sa)
// y_in = -sa*X + ca*Y + cy,  cy = CENTER*(1 - ca + sa)
// Fixed fmaf chain: corner extremes == sample extremes (monotone per variable).
__device__ __forceinline__ void map_coords(float ca, float sa, float cx, float cy,
                                           float Xf, float Yf,
                                           float& x_in, float& y_in) {
    const float fx0 = fmaf(ca, Xf, cx);
    const float fy0 = fmaf(-sa, Xf, cy);
    x_in = fmaf(sa, Yf, fx0);
    y_in = fmaf(ca, Yf, fy0);
}

// Async global->LDS DMA. 4B: lane i -> l + i*4. 16B: lane i -> l + i*16.
// LDS base wave-uniform; global ptr per-lane. Barrier's vmcnt(0) drains.
__device__ __forceinline__ void gload_lds4(const float* g, float* l) {
    __builtin_amdgcn_global_load_lds((const __attribute__((address_space(1))) void*)g,
                                     (__attribute__((address_space(3))) void*)l, 4, 0, 0);
}
__device__ __forceinline__ void gload_lds16(const float* g, float* l) {
    __builtin_amdgcn_global_load_lds((const __attribute__((address_space(1))) void*)g,
                                     (__attribute__((address_space(3))) void*)l, 16, 0, 0);
}

// Per-tile block-uniform params, computed by wave 0 into an LDS ring.
// flags: bit0 = empty (fully outside image), bit1 = interior (no clamps needed)
__device__ __forceinline__ void compute_params(int* dst, float X0f, float Y0f,
                                               float sa, float ca, float cx, float cy,
                                               bool wide, bool store) {
    float x00, y00, x01, y01, x10, y10, x11, y11;
    map_coords(ca, sa, cx, cy, X0f,         Y0f,         x00, y00);
    map_coords(ca, sa, cx, cy, X0f + 63.f,  Y0f,         x01, y01);
    map_coords(ca, sa, cx, cy, X0f,         Y0f + 63.f,  x10, y10);
    map_coords(ca, sa, cx, cy, X0f + 63.f,  Y0f + 63.f,  x11, y11);
    const float xmin = fminf(fminf(x00, x01), fminf(x10, x11));
    const float xmax = fmaxf(fmaxf(x00, x01), fmaxf(x10, x11));
    const float ymin = fminf(fminf(y00, y01), fminf(y10, y11));
    const float ymax = fmaxf(fmaxf(y00, y01), fmaxf(y10, y11));
    const int ix0_raw = (int)floorf(xmin);
    const int ix1_raw = (int)floorf(xmax) + 1;
    const int iy0_raw = (int)floorf(ymin);
    const int iy1_raw = (int)floorf(ymax) + 1;
    const int ix0 = max(0, ix0_raw), ix1 = min(N_IMG - 1, ix1_raw);
    const int iy0 = max(0, iy0_raw), iy1 = min(N_IMG - 1, iy1_raw);
    int win, dB = 0;
    if (wide) {                      // 96-px 16B-aligned window covers bbox (<=95)
        win = min(ix0 & ~3, N_IMG - 96);
    } else {                         // dual 64-px full-wave segments
        win = min(ix0, N_IMG - 64);
        dB  = max(win, ix1 - 63) - win;    // 0..28
    }
    int flags = ((ix1 < ix0) || (iy1 < iy0)) ? 1 : 0;
    flags |= ((ix0_raw >= 0) && (ix1_raw <= N_IMG - 1) &&
              (iy0_raw >= 0) && (iy1_raw <= N_IMG - 1)) ? 2 : 0;
    if (store) {
        dst[0] = iy0; dst[1] = iy1 - iy0 + 1; dst[2] = win; dst[3] = dB; dst[4] = flags;
    }
}

// Shallow staging: contiguous h*96 tile via 16B async DMA (1 KB / wave-instr).
__device__ __forceinline__ void stage_wide(const float* __restrict__ img, float* buf,
                                           int lane, int wv, int iy0, int h, int win) {
    const int D = h * 96;
    for (int o = wv * 256; o < D; o += NWAVES * 256) {
        const int d = o + 4 * lane;
        const int r = (unsigned)d / 96u;            // overshoot rows clamp below
        const int c = d - r * 96;
        const int gr = min(iy0 + r, N_IMG - 1);
        gload_lds16(img + (size_t)gr * N_IMG + win + c, buf + o);
    }
}

// Steep staging: per-row dual 64-px 4B async DMA, odd stride (95/97) for
// conflict-free reads (bank ~ x -+ y, lane step in [1,1.414]).
template<int STRIDE>
__device__ __forceinline__ void stage_steep(const float* __restrict__ img, float* buf,
                                            int lane, int wv, int iy0, int h,
                                            int win, int dB) {
    const float* g = img + (size_t)(iy0 + wv) * N_IMG + win + lane;
    float* l = buf + wv * STRIDE;
    for (int r = wv; r < h; r += NWAVES) {
        gload_lds4(g, l);
        if (dB > 0) gload_lds4(g + dB, l + dB);
        g += NWAVES * N_IMG;
        l += NWAVES * STRIDE;
    }
}

// Bilinear sampler; incremental coords (<=7 adds, drift <=4e-4 px, buffer padded
// so +-1 floor overshoot stays in-bounds; overshoot weight ~1e-4 -> error ~1e-3).
template<int STRIDE>
__device__ __forceinline__ float sample_tile(const float* __restrict__ tile,
                                             float sa, float ca,
                                             float x_in, float y_in,
                                             float basef, int iy0, int win,
                                             bool interior) {
    float acc = 0.0f;
    const float Sf = (float)STRIDE;
    if (interior) {
        #pragma unroll
        for (int i = 0; i < YPT; ++i) {
            const float x0f = floorf(x_in);
            const float y0f = floorf(y_in);
            const float wx  = x_in - x0f;
            const float wy  = y_in - y0f;
            const int li = (int)(fmaf(y0f, Sf, x0f) + basef);   // exact in fp32
            const float t00 = tile[li];
            const float t01 = tile[li + 1];
            const float t10 = tile[li + STRIDE];
            const float t11 = tile[li + STRIDE + 1];
            const float top = fmaf(wx, t01 - t00, t00);
            const float bot = fmaf(wx, t11 - t10, t10);
            acc += fmaf(wy, bot - top, top);
            x_in += sa; y_in += ca;
        }
    } else {
        #pragma unroll
        for (int i = 0; i < YPT; ++i) {
            const float x0f = floorf(x_in);
            const float y0f = floorf(y_in);
            const float wx  = x_in - x0f;
            const float wy  = y_in - y0f;
            const int x0 = (int)x0f;
            const int y0 = (int)y0f;
            const int x0c = min(max(x0,     0), N_IMG - 1);
            const int x1c = min(max(x0 + 1, 0), N_IMG - 1);
            const int y0c = min(max(y0,     0), N_IMG - 1);
            const int y1c = min(max(y0 + 1, 0), N_IMG - 1);
            const float wxa = (x0     >= 0 && x0     < N_IMG) ? (1.0f - wx) : 0.0f;
            const float wxb = (x0 + 1 >= 0 && x0 + 1 < N_IMG) ? wx          : 0.0f;
            const float wya = (y0     >= 0 && y0     < N_IMG) ? (1.0f - wy) : 0.0f;
            const float wyb = (y0 + 1 >= 0 && y0 + 1 < N_IMG) ? wy          : 0.0f;
            const int r0 = (y0c - iy0) * STRIDE - win;
            const int r1 = (y1c - iy0) * STRIDE - win;
            const float t00 = tile[r0 + x0c];
            const float t01 = tile[r0 + x1c];
            const float t10 = tile[r1 + x0c];
            const float t11 = tile[r1 + x1c];
            acc += wya * fmaf(wxa, t00, wxb * t01)
                 + wyb * fmaf(wxa, t10, wxb * t11);
            x_in += sa; y_in += ca;
        }
    }
    return acc;
}

// Prefetch pipeline over the 16 y-tiles of one (X-tile, angle) block:
//   iter t: [stage t+1 -> buf B (async)] [wave0: params t+2] [sample t from buf A]
//           [barrier: drains B's DMAs (hidden behind sampling t), publishes params]
template<int STRIDE>
__device__ __forceinline__ void run_pipeline(const float* __restrict__ img,
                                             float* __restrict__ out,
                                             int X0, int a,
                                             float sa, float ca, float cx, float cy,
                                             int lane, int wv, int tid,
                                             int (*ipar)[5]) {
    constexpr bool WIDE = (STRIDE == 96);
    float* buf0 = smem;
    float* buf1 = smem + BUF_WORDS;
    const float X0f = (float)X0;

    // ---- prologue: params(0), stage(0), params(1), one exposed drain ----
    if (wv == 0)
        compute_params(ipar[0], X0f, 0.0f, sa, ca, cx, cy, WIDE, tid == 0);
    __syncthreads();
    {
        const int* p = ipar[0];
        if (!(p[4] & 1)) {
            if (WIDE) stage_wide(img, buf0, lane, wv, p[0], p[1], p[2]);
            else      stage_steep<STRIDE>(img, buf0, lane, wv, p[0], p[1], p[2], p[3]);
        }
    }
    if (wv == 0)
        compute_params(ipar[1], X0f, (float)TILE, sa, ca, cx, cy, WIDE, tid == 0);
    __syncthreads();

    const float Xf  = X0f + (float)lane;
    const float fx0 = fmaf(ca, Xf, cx);
    const float fy0 = fmaf(-sa, Xf, cy);

    float acc = 0.0f;
    for (int t = 0; t < NTILES; ++t) {
        const int* pt = ipar[t % 3];          // tile-t params (slot safe: mod-3 ring)
        const int iy0 = pt[0], win = pt[2], fl = pt[4];

        if (t + 1 < NTILES) {                 // issue async staging for t+1
            const int* pn = ipar[(t + 1) % 3];
            if (!(pn[4] & 1)) {
                float* nb = ((t + 1) & 1) ? buf1 : buf0;
                if (WIDE) stage_wide(img, nb, lane, wv, pn[0], pn[1], pn[2]);
                else      stage_steep<STRIDE>(img, nb, lane, wv, pn[0], pn[1], pn[2], pn[3]);
            }
        }
        if (wv == 0 && t + 2 < NTILES)        // params for t+2 into free ring slot
            compute_params(ipar[(t + 2) % 3], X0f, (float)((t + 2) * TILE),
                           sa, ca, cx, cy, WIDE, tid == 0);

        if (!(fl & 1)) {                      // sample tile t (hides t+1's DMAs)
            const float Ybf  = (float)(t * TILE + wv * YPT);
            const float x_in = fmaf(sa, Ybf, fx0);
            const float y_in = fmaf(ca, Ybf, fy0);
            acc += sample_tile<STRIDE>((t & 1) ? buf1 : buf0, sa, ca, x_in, y_in,
                                       -(float)(iy0 * STRIDE + win), iy0, win,
                                       (fl & 2) != 0);
        }
        __syncthreads();                      // drain t+1 DMAs; publish params t+2
    }

    // ---- block reduce (overlay buf0; last sampling used buf1) -> final out ----
    smem[wv * 64 + lane] = acc;
    __syncthreads();
    if (wv == 0) {
        float s = 0.0f;
        #pragma unroll
        for (int w = 0; w < NWAVES; ++w) s += smem[w * 64 + lane];
        out[(size_t)(X0 + lane) * N_VIEWS + a] = s;
    }
}

__global__ __launch_bounds__(NTHREADS) void radon_full(const float* __restrict__ img,
                                                       const float* __restrict__ theta,
                                                       float* __restrict__ out) {
    __shared__ int ipar[3][5];
    const int X0  = blockIdx.x * TILE;
    const int a   = blockIdx.y;
    const int tid = threadIdx.x;
    const int lane = tid & 63;
    const int wv   = tid >> 6;

    const float ang = theta[a] * 0.017453292519943295f;
    float sa, ca;
    __sincosf(ang, &sa, &ca);
    const float cx = (float)CENTER * (1.0f - ca - sa);
    const float cy = (float)CENTER * (1.0f - ca + sa);

    // Block-uniform path: shallow (|ca|>0.707) -> wide DMA stride 96;
    // steep -> dual-segment 4B DMA, stride 95 (ca>0) / 97 (ca<=0).
    if (fabsf(ca) > 0.7072f)
        run_pipeline<96>(img, out, X0, a, sa, ca, cx, cy, lane, wv, tid, ipar);
    else if (ca > 0.0f)
        run_pipeline<95>(img, out, X0, a, sa, ca, cx, cy, lane, wv, tid, ipar);
    else
        run_pipeline<97>(img, out, X0, a, sa, ca, cx, cy, lane, wv, tid, ipar);
}

extern "C" void kernel_launch(void* const* d_in, const int* in_sizes, int n_in,
                              void* d_out, int out_size, void* d_ws, size_t ws_size,
                              hipStream_t stream) {
    const float* img   = (const float*)d_in[0];   // [1024, 1024] f32
    const float* theta = (const float*)d_in[1];   // [90] f32 degrees
    float* out = (float*)d_out;                   // [1024, 90] f32

    // One dispatch: block = (X-tile, angle); every block writes its 64 outputs
    // unconditionally -> no memset, no workspace, no reduce kernel.
    dim3 grid(N_IMG / TILE, N_VIEWS);             // 16 x 90 = 1440 blocks
    radon_full<<<grid, NTHREADS, 2 * BUF_WORDS * sizeof(float), stream>>>(img, theta, out);
}

// Round 10
// 141.176 us; speedup vs baseline: 1.1308x; 1.1308x over previous
//
#include <hip/hip_runtime.h>

#define N_IMG   1024
#define N_VIEWS 90
#define CENTER  512
#define TILE    64
#define NYB     (N_IMG / TILE)      // 16 y-blocks
#define NTHREADS 512
#define NWAVES   8
#define YPT      (TILE / NWAVES)    // 8 samples per thread
#define TILE_WORDS 9216             // >= 93*97+95 (raw-bbox + drift pad); 36.9 KB

// x_in =  ca*X + sa*Y + cx,  cx = CENTER*(1 - ca - sa)
// y_in = -sa*X + ca*Y + cy,  cy = CENTER*(1 - ca + sa)
// Fixed fmaf chain: corner extremes == sample extremes (monotone per variable),
// so the bbox from the 4 corners bounds every sample's floor exactly.
__device__ __forceinline__ void map_coords(float ca, float sa, float cx, float cy,
                                           float Xf, float Yf,
                                           float& x_in, float& y_in) {
    const float fx0 = fmaf(ca, Xf, cx);
    const float fy0 = fmaf(-sa, Xf, cy);
    x_in = fmaf(sa, Yf, fx0);
    y_in = fmaf(ca, Yf, fy0);
}

// Async global->LDS DMA. 4B: lane i -> l + i*4. 16B: lane i -> l + i*16.
// LDS base wave-uniform; global ptr per-lane. __syncthreads() drains vmcnt.
__device__ __forceinline__ void gload_lds4(const float* g, float* l) {
    __builtin_amdgcn_global_load_lds((const __attribute__((address_space(1))) void*)g,
                                     (__attribute__((address_space(3))) void*)l, 4, 0, 0);
}
__device__ __forceinline__ void gload_lds16(const float* g, float* l) {
    __builtin_amdgcn_global_load_lds((const __attribute__((address_space(1))) void*)g,
                                     (__attribute__((address_space(3))) void*)l, 16, 0, 0);
}

// Fast bilinear sampler — the ONLY sample path. Window guarantees every tap
// (y0,y0+1)x(x0,x0+1) maps inside the staged buffer (zeros where off-image).
// Incremental coords: <=7 adds, drift <=4e-4 px; buffer padded for overshoot.
template<int STRIDE>
__device__ __forceinline__ float sample_tile(const float* __restrict__ tile,
                                             float sa, float ca,
                                             float x_in, float y_in, float basef) {
    float acc = 0.0f;
    const float Sf = (float)STRIDE;
    #pragma unroll
    for (int i = 0; i < YPT; ++i) {
        const float x0f = floorf(x_in);
        const float y0f = floorf(y_in);
        const float wx  = x_in - x0f;
        const float wy  = y_in - y0f;
        const int li = (int)(fmaf(y0f, Sf, x0f) + basef);   // exact in fp32
        const float t00 = tile[li];             // ds_read2 (0,1)
        const float t01 = tile[li + 1];
        const float t10 = tile[li + STRIDE];    // ds_read2 (S,S+1) same base
        const float t11 = tile[li + STRIDE + 1];
        const float top = fmaf(wx, t01 - t00, t00);
        const float bot = fmaf(wx, t11 - t10, t10);
        acc += fmaf(wy, bot - top, top);
        x_in += sa; y_in += ca;
    }
    return acc;
}

__global__ __launch_bounds__(NTHREADS) void radon_tile(const float* __restrict__ img,
                                                       const float* __restrict__ theta,
                                                       float* __restrict__ partial,
                                                       float* __restrict__ out,
                                                       int mode) {
    __shared__ float tile[TILE_WORDS];   // 36.9 KB -> 4 blocks/CU, 32 waves
    __shared__ float fpar[4];            // sa, ca, cx, cy
    __shared__ int   ipar[8];            // iy0w, h(unused rows cnt), win, dB, path, flags, ry0, nrows

    const int a  = blockIdx.z;
    const int X0 = blockIdx.x * TILE;
    const int Y0 = blockIdx.y * TILE;
    const int tid  = threadIdx.x;
    const int lane = tid & 63;
    const int wv   = tid >> 6;            // 0..7

    // ---- wave 0 computes all block-uniform params once ----
    if (wv == 0) {
        const float ang = theta[a] * 0.017453292519943295f;
        float sa, ca;
        __sincosf(ang, &sa, &ca);
        const float cx = (float)CENTER * (1.0f - ca - sa);
        const float cy = (float)CENTER * (1.0f - ca + sa);

        float x00, y00, x01, y01, x10, y10, x11, y11;
        map_coords(ca, sa, cx, cy, (float)X0,        (float)Y0,        x00, y00);
        map_coords(ca, sa, cx, cy, (float)(X0 + 63), (float)Y0,        x01, y01);
        map_coords(ca, sa, cx, cy, (float)X0,        (float)(Y0 + 63), x10, y10);
        map_coords(ca, sa, cx, cy, (float)(X0 + 63), (float)(Y0 + 63), x11, y11);
        const float xmin = fminf(fminf(x00, x01), fminf(x10, x11));
        const float xmax = fmaxf(fmaxf(x00, x01), fmaxf(x10, x11));
        const float ymin = fminf(fminf(y00, y01), fminf(y10, y11));
        const float ymax = fmaxf(fmaxf(y00, y01), fmaxf(y10, y11));

        const int ix0_raw = (int)floorf(xmin);
        const int ix1_raw = (int)floorf(xmax) + 1;   // max x-tap; span <= 91
        const int iy0_raw = (int)floorf(ymin);
        const int iy1_raw = (int)floorf(ymax) + 1;   // max y-tap; span <= 91

        const bool empty = (ix1_raw < 0) || (ix0_raw > N_IMG - 1) ||
                           (iy1_raw < 0) || (iy0_raw > N_IMG - 1);
        const bool interior = (ix0_raw >= 0) && (ix1_raw <= N_IMG - 1) &&
                              (iy0_raw >= 0) && (iy1_raw <= N_IMG - 1);

        int path = (fabsf(ca) > 0.7072f) ? 0 : ((ca > 0.0f) ? 1 : 2);
        int iy0w, win, dB = 0, ry0 = 0, nrows = 0;
        if (interior) {
            iy0w = iy0_raw;
            if (path == 0) {
                win = min(ix0_raw & ~3, N_IMG - 96);          // 96-px in-image window
            } else {
                win = min(ix0_raw, N_IMG - 64);               // dual 64-px segments
                dB  = max(win, ix1_raw - 63) - win;           // 0..28
            }
            nrows = iy1_raw - iy0_raw + 1;                    // <= 92 (staged rows)
        } else {
            // border: RAW (unclamped) 4-aligned window; zeros pad off-image.
            iy0w = iy0_raw;
            win  = ix0_raw & ~3;                              // col offset <= 94 < 95
            ry0  = max(0, iy0_raw);                           // in-image rows to stage
            nrows = min(N_IMG - 1, iy1_raw) - ry0 + 1;
        }
        if (tid == 0) {
            fpar[0] = sa; fpar[1] = ca; fpar[2] = cx; fpar[3] = cy;
            ipar[0] = iy0w; ipar[1] = nrows; ipar[2] = win; ipar[3] = dB;
            ipar[4] = path;
            ipar[5] = empty ? 1 : (interior ? 2 : 0);
            ipar[6] = ry0;
        }
    }
    __syncthreads();

    float* __restrict__ pslot = partial + ((size_t)(a * NYB + blockIdx.y) << 10) + X0;
    const int flags = ipar[5];

    if (flags & 1) {                        // tile maps fully outside image
        if (mode == 0 && tid < 64) pslot[tid] = 0.0f;
        return;                             // mode 1: out pre-zeroed
    }

    const float sa = fpar[0], ca = fpar[1], cx = fpar[2], cy = fpar[3];
    const int iy0 = ipar[0], nrows = ipar[1], win = ipar[2], dB = ipar[3];
    const int path = ipar[4];
    const int S = (path == 0) ? 96 : ((path == 1) ? 95 : 97);

    if (flags & 2) {
        // ---- interior staging: async DMA (no VGPR round-trip) ----
        if (path == 0) {
            const int D = nrows * 96;
            for (int o = wv * 256; o < D; o += NWAVES * 256) {
                const int d = o + 4 * lane;
                const int r = (unsigned)d / 96u;
                const int c = d - r * 96;
                const int gr = min(iy0 + r, N_IMG - 1);       // overshoot clamp
                gload_lds16(img + (size_t)gr * N_IMG + win + c, tile + o);
            }
        } else {
            const float* g = img + (size_t)(iy0 + wv) * N_IMG + win + lane;
            float* l = tile + wv * S;
            for (int r = wv; r < nrows; r += NWAVES) {
                gload_lds4(g, l);
                if (dB > 0) gload_lds4(g + dB, l + dB);
                g += NWAVES * N_IMG;
                l += NWAVES * S;
            }
        }
    } else {
        // ---- border staging: zero-fill, then guarded float4 copy of the
        //      in-image intersection; samples then use the SAME fast path ----
        for (int o4 = tid; o4 < TILE_WORDS / 4; o4 += NTHREADS)
            *(float4*)(tile + 4 * o4) = make_float4(0.f, 0.f, 0.f, 0.f);
        __syncthreads();
        const int ry0 = ipar[6];
        const int cx0 = max(0, win);                          // 4-aligned
        const int cxe = min(N_IMG - 1, win + 94);             // last needed col
        const int wIn = cxe - cx0 + 1;                        // 1..95
        const int n4  = wIn >> 2;                             // full float4 chunks
        const int items = nrows * 24;
        for (int idx = tid; idx < items; idx += NTHREADS) {
            const int r  = (unsigned)idx / 24u;
            const int c4 = idx - r * 24;
            const int gy = ry0 + r;
            float* dst = tile + (gy - iy0) * S + (cx0 - win) + 4 * c4;
            const float* src = img + (size_t)gy * N_IMG + cx0 + 4 * c4;
            if (c4 < n4) {
                *(float4*)dst = *(const float4*)src;          // ds_write_b128
            } else if (c4 == n4) {
                for (int j = 0; j < (wIn & 3); ++j) dst[j] = src[j];
            }
        }
    }
    __syncthreads();

    // ---- per-lane sample line; single fast path ----
    const float Xf  = (float)(X0 + lane);
    const float fx0 = fmaf(ca, Xf, cx);
    const float fy0 = fmaf(-sa, Xf, cy);
    const float Ybf = (float)(Y0 + wv * YPT);
    const float x_in = fmaf(sa, Ybf, fx0);
    const float y_in = fmaf(ca, Ybf, fy0);
    const float basef = -(float)(iy0 * S + win);

    float acc;
    if (path == 0)      acc = sample_tile<96>(tile, sa, ca, x_in, y_in, basef);
    else if (path == 1) acc = sample_tile<95>(tile, sa, ca, x_in, y_in, basef);
    else                acc = sample_tile<97>(tile, sa, ca, x_in, y_in, basef);

    // ---- block reduce, overlaying tile; plain store (mode 0) or atomic ----
    __syncthreads();                        // all waves done reading tile
    tile[wv * 64 + lane] = acc;
    __syncthreads();
    if (wv == 0) {
        float s = 0.0f;
        #pragma unroll
        for (int w = 0; w < NWAVES; ++w) s += tile[w * 64 + lane];
        if (mode == 0) pslot[lane] = s;
        else           atomicAdd(&out[(X0 + lane) * N_VIEWS + a], s);
    }
}

__global__ __launch_bounds__(256) void reduce_partials(const float* __restrict__ partial,
                                                       float* __restrict__ out) {
    const int g = blockIdx.x * 256 + threadIdx.x;   // [0, 90*1024)
    const int a = g >> 10;
    const int X = g & 1023;
    float s = 0.0f;
    #pragma unroll
    for (int yb = 0; yb < NYB; ++yb)
        s += partial[((size_t)(a * NYB + yb) << 10) + X];
    out[X * N_VIEWS + a] = s;
}

extern "C" void kernel_launch(void* const* d_in, const int* in_sizes, int n_in,
                              void* d_out, int out_size, void* d_ws, size_t ws_size,
                              hipStream_t stream) {
    const float* img   = (const float*)d_in[0];   // [1024, 1024] f32
    const float* theta = (const float*)d_in[1];   // [90] f32 degrees
    float* out     = (float*)d_out;               // [1024, 90] f32
    float* partial = (float*)d_ws;                // [90][16][1024] f32 partials

    const size_t needed = (size_t)N_VIEWS * NYB * N_IMG * sizeof(float);  // 5.9 MB
    const int mode = (ws_size >= needed) ? 0 : 1;
    if (mode == 1)
        hipMemsetAsync(d_out, 0, (size_t)out_size * sizeof(float), stream);

    dim3 grid(N_IMG / TILE, N_IMG / TILE, N_VIEWS);   // 16 x 16 x 90, one dispatch
    radon_tile<<<grid, NTHREADS, 0, stream>>>(img, theta, partial, out, mode);

    if (mode == 0)
        reduce_partials<<<(N_VIEWS * N_IMG) / 256, 256, 0, stream>>>(partial, out);
}